// Round 10
// baseline (762.258 us; speedup 1.0000x reference)
//
#include <hip/hip_runtime.h>
#include <hip/hip_bf16.h>

#define NTOK 1024
#define HDIM 2880
#define IDIM 2880
#define NEXP 8
#define BK 64
#define NT 45  // HDIM/BK

typedef __attribute__((ext_vector_type(4))) float fx4;
typedef __attribute__((ext_vector_type(8))) short sx8;
typedef __attribute__((ext_vector_type(8))) unsigned short usx8;

typedef const __attribute__((address_space(1))) void* gas_p;
typedef __attribute__((address_space(3))) void* las_p;

__device__ __forceinline__ unsigned short f2bf(float f) {
  __hip_bfloat16 b = __float2bfloat16(f);
  return __builtin_bit_cast(unsigned short, b);
}
__device__ __forceinline__ usx8 cvt8(fx4 a, fx4 b) {
  usx8 u = {f2bf(a.x), f2bf(a.y), f2bf(a.z), f2bf(a.w),
            f2bf(b.x), f2bf(b.y), f2bf(b.z), f2bf(b.w)};
  return u;
}

#define MFMA16(a, b, c) __builtin_amdgcn_mfma_f32_16x16x32_bf16(a, b, c, 0, 0, 0)

__global__ __launch_bounds__(256) void init_out_k(const float* __restrict__ x,
                                                  float* __restrict__ out) {
  int i = blockIdx.x * 256 + threadIdx.x;
  ((fx4*)out)[i] = ((const fx4*)x)[i];
}

__global__ __launch_bounds__(256) void rms_router_k(
    const float* __restrict__ x, const float* __restrict__ norm_w,
    const float* __restrict__ gate_w, const float* __restrict__ gate_b,
    unsigned short* __restrict__ t_bf, int* __restrict__ cnt,
    int* __restrict__ tok, float* __restrict__ wgt) {
  const int n = blockIdx.x;
  const int tid = threadIdx.x;
  const int wid = tid >> 6, lane = tid & 63;
  const float* xr = x + (size_t)n * HDIM;

  float ss = 0.f;
  for (int h = tid; h < HDIM; h += 256) { float v = xr[h]; ss += v * v; }
  #pragma unroll
  for (int o = 32; o > 0; o >>= 1) ss += __shfl_down(ss, o);
  __shared__ float sred[4];
  if (lane == 0) sred[wid] = ss;
  __syncthreads();
  const float rstd =
      rsqrtf((sred[0] + sred[1] + sred[2] + sred[3]) * (1.0f / HDIM) + 1e-5f);

  float p[NEXP];
  #pragma unroll
  for (int e = 0; e < NEXP; e++) p[e] = 0.f;
  for (int h = tid; h < HDIM; h += 256) {
    float xv = xr[h] * norm_w[h];
    t_bf[(size_t)n * HDIM + h] = f2bf(xv * rstd);
    #pragma unroll
    for (int e = 0; e < NEXP; e++) p[e] += xv * gate_w[e * HDIM + h];
  }
  __shared__ float pls[4][NEXP];
  #pragma unroll
  for (int e = 0; e < NEXP; e++) {
    float v = p[e];
    #pragma unroll
    for (int o = 32; o > 0; o >>= 1) v += __shfl_down(v, o);
    if (lane == 0) pls[wid][e] = v;
  }
  __syncthreads();
  if (tid == 0) {
    float lg[NEXP];
    #pragma unroll
    for (int e = 0; e < NEXP; e++)
      lg[e] = (pls[0][e] + pls[1][e] + pls[2][e] + pls[3][e]) * rstd + gate_b[e];
    unsigned used = 0;
    float val[4];
    int idx[4];
    for (int k = 0; k < 4; k++) {
      float best = -1e30f;
      int bi = 0;
      for (int e = 0; e < NEXP; e++)
        if (!((used >> e) & 1u) && lg[e] > best) { best = lg[e]; bi = e; }
      used |= 1u << bi;
      val[k] = best;
      idx[k] = bi;
    }
    float sum = 0.f, w[4];
    for (int k = 0; k < 4; k++) { w[k] = expf(val[k] - val[0]); sum += w[k]; }
    for (int k = 0; k < 4; k++) {
      int e = idx[k];
      int slot = atomicAdd(&cnt[e], 1);
      tok[e * NTOK + slot] = n;
      wgt[e * NTOK + slot] = w[k] / sum;
    }
  }
}

// GEMM1: BM=256 tokens x 96 I-cols x {G,L}, BK=64, 8 waves (4m x 2n).
// Full dbuf (A 2x32KB gload_lds, B 2x24KB reg-staged), issue-early /
// write-late, one cheap-drain barrier per tile.
__global__ __launch_bounds__(512, 2) void gemm1_k(
    const unsigned short* __restrict__ t_bf,
    const float* __restrict__ w_gate_up, const float* __restrict__ b_gate_up,
    const int* __restrict__ cnt, const int* __restrict__ tok,
    unsigned short* __restrict__ act_bf) {
  const int h = blockIdx.x;
  // u = uhi*8 + (h&7); z = (h>>3)&3 : z-twins share h%8 (same XCD), 8 apart.
  const int u = (h >> 5) * 8 + (h & 7);
  const int z = (h >> 3) & 3;
  const int e = u / 30;
  const int c0 = (u % 30) * 96;
  const int m0 = z * 256;
  const int ce = cnt[e];
  if (m0 >= ce) return;

  const int tid = threadIdx.x, lane = tid & 63, wid = tid >> 6;
  const int fr = lane & 15, fq = lane >> 4;
  const int wm = wid >> 1, wn = wid & 1;

  __shared__ __align__(16) unsigned short Ash[2][256 * 64];  // 64 KB
  __shared__ __align__(16) unsigned short Bsh[2][192 * 64];  // 48 KB (G:0-95 L:96-191)

  const fx4 FZ = {0.f, 0.f, 0.f, 0.f};
  fx4 accG[4][3], accL[4][3];
  #pragma unroll
  for (int m = 0; m < 4; m++)
    #pragma unroll
    for (int n = 0; n < 3; n++) { accG[m][n] = FZ; accL[m][n] = FZ; }

  // A gather bases: pre-swizzled source chunk (verified conflict-free).
  const unsigned short* gA[4];
  #pragma unroll
  for (int j = 0; j < 4; ++j) {
    int R = m0 + wid * 32 + j * 8 + (lane >> 3);
    int rc = R < ce ? R : ce - 1;
    gA[j] = t_bf + (size_t)tok[e * NTOK + rc] * HDIM +
            ((lane & 7) ^ ((lane >> 3) & 7)) * 8;
  }
  // B: 192 rows x 8 chunks = 1536 slots; thread covers slot tid + 512q.
  const float* wb = w_gate_up + (size_t)e * (2 * IDIM) * HDIM;
  const float* srcB[3];
  int bR[3], bC[3];
  #pragma unroll
  for (int q = 0; q < 3; ++q) {
    int s = tid + 512 * q;
    bR[q] = s >> 3;
    bC[q] = s & 7;
    int wrow = bR[q] < 96 ? (c0 + bR[q]) : (IDIM + c0 + (bR[q] - 96));
    srcB[q] = wb + (size_t)wrow * HDIM + bC[q] * 8;
  }

  fx4 Ra[6], Rb[6];
  #define G1_LOADB(R, k)                                                       \
    {                                                                          \
      _Pragma("unroll") for (int q = 0; q < 3; ++q) {                          \
        R[2 * q] = *(const fx4*)(srcB[q] + (k));                               \
        R[2 * q + 1] = *(const fx4*)(srcB[q] + (k) + 4);                       \
      }                                                                        \
    }
  #define G1_WRITEB(R, bb)                                                     \
    {                                                                          \
      _Pragma("unroll") for (int q = 0; q < 3; ++q)                            \
          *(usx8*)&Bsh[bb][bR[q] * 64 + ((bC[q] ^ (bR[q] & 7)) * 8)] =         \
              cvt8(R[2 * q], R[2 * q + 1]);                                    \
    }
  #define G1_DMA_A(kt, ab)                                                     \
    {                                                                          \
      _Pragma("unroll") for (int j = 0; j < 4; ++j)                            \
          __builtin_amdgcn_global_load_lds(                                    \
              (gas_p)(gA[j] + (size_t)(kt)*BK),                                \
              (las_p)&Ash[ab][(wid * 32 + j * 8) * 64], 16, 0, 0);             \
    }
  #define G1_COMPUTE(ab, bb)                                                   \
    {                                                                          \
      _Pragma("unroll") for (int ks = 0; ks < 2; ++ks) {                       \
        const int rc = ks * 4 + fq;                                            \
        sx8 aF[4], bG[3], bL[3];                                               \
        _Pragma("unroll") for (int m = 0; m < 4; ++m) aF[m] =                  \
            *(const sx8*)&Ash[ab][(wm * 64 + m * 16 + fr) * 64 +               \
                                  ((rc ^ (fr & 7)) * 8)];                      \
        _Pragma("unroll") for (int n = 0; n < 3; ++n) {                        \
          bG[n] = *(const sx8*)&Bsh[bb][(wn * 48 + n * 16 + fr) * 64 +         \
                                        ((rc ^ (fr & 7)) * 8)];                \
          bL[n] = *(const sx8*)&Bsh[bb][(96 + wn * 48 + n * 16 + fr) * 64 +    \
                                        ((rc ^ (fr & 7)) * 8)];                \
        }                                                                      \
        __builtin_amdgcn_s_setprio(1);                                         \
        _Pragma("unroll") for (int n = 0; n < 3; ++n)                          \
            _Pragma("unroll") for (int m = 0; m < 4; ++m) {                    \
          accG[m][n] = MFMA16(aF[m], bG[n], accG[m][n]);                       \
          accL[m][n] = MFMA16(aF[m], bL[n], accL[m][n]);                       \
        }                                                                      \
        __builtin_amdgcn_s_setprio(0);                                         \
      }                                                                        \
    }

  // prologue: stage tile 0 (A->buf0, B0->Bsh0), B1 into Rb
  G1_LOADB(Ra, 0);
  G1_LOADB(Rb, BK);
  G1_DMA_A(0, 0);
  __syncthreads();  // startup drain (once)
  G1_WRITEB(Ra, 0);
  __syncthreads();

  for (int tt = 0; tt < 22; ++tt) {
    const int t0 = 2 * tt;
    // EVEN tile t0 (bufs 0)
    G1_DMA_A(t0 + 1, 1);
    G1_LOADB(Ra, (t0 + 2) * BK);
    G1_COMPUTE(0, 0);
    G1_WRITEB(Rb, 1);  // B(t0+1)
    __syncthreads();
    // ODD tile t0+1 (bufs 1)
    G1_DMA_A(t0 + 2, 0);
    const int kodd = (t0 + 3 < NT) ? (t0 + 3) * BK : 0;
    G1_LOADB(Rb, kodd);
    G1_COMPUTE(1, 1);
    G1_WRITEB(Ra, 0);  // B(t0+2)
    __syncthreads();
  }
  G1_COMPUTE(0, 0);  // tile 44

  #pragma unroll
  for (int n = 0; n < 3; ++n) {
    const int col = c0 + wn * 48 + n * 16 + fr;
    const float bg = b_gate_up[e * (2 * IDIM) + col];
    const float bl = b_gate_up[e * (2 * IDIM) + IDIM + col];
    #pragma unroll
    for (int m = 0; m < 4; ++m) {
      #pragma unroll
      for (int r = 0; r < 4; ++r) {
        int slot = m0 + wm * 64 + m * 16 + fq * 4 + r;
        if (slot < ce) {
          float g = accG[m][n][r] + bg;
          float l = accL[m][n][r] + bl;
          float a = g * (1.0f / (1.0f + __expf(-1.702f * g))) * (l + 1.0f);
          act_bf[((size_t)e * NTOK + slot) * IDIM + col] = f2bf(a);
        }
      }
    }
  }
}

// GEMM2: BM=256 x 192 cols, BK=64, 8 waves (4m x 2n). Same pipeline.
__global__ __launch_bounds__(512, 2) void gemm2_k(
    const unsigned short* __restrict__ act_bf, const float* __restrict__ w_down,
    const float* __restrict__ b_down, const int* __restrict__ cnt,
    const int* __restrict__ tok, const float* __restrict__ wgt,
    float* __restrict__ out) {
  const int h = blockIdx.x;
  const int u = (h >> 5) * 8 + (h & 7);
  const int z = (h >> 3) & 3;
  const int e = u / 15;
  const int c0 = (u % 15) * 192;
  const int m0 = z * 256;
  const int ce = cnt[e];
  if (m0 >= ce) return;

  const int tid = threadIdx.x, lane = tid & 63, wid = tid >> 6;
  const int fr = lane & 15, fq = lane >> 4;
  const int wm = wid >> 1, wn = wid & 1;

  __shared__ __align__(16) unsigned short Ash[2][256 * 64];  // 64 KB
  __shared__ __align__(16) unsigned short Bsh[2][192 * 64];  // 48 KB

  const fx4 FZ = {0.f, 0.f, 0.f, 0.f};
  fx4 acc[4][6];
  #pragma unroll
  for (int m = 0; m < 4; m++)
    #pragma unroll
    for (int n = 0; n < 6; n++) acc[m][n] = FZ;

  const unsigned short* gA[4];
  #pragma unroll
  for (int j = 0; j < 4; ++j) {
    int R = m0 + wid * 32 + j * 8 + (lane >> 3);
    int rc = R < ce ? R : ce - 1;
    gA[j] = act_bf + ((size_t)e * NTOK + rc) * IDIM +
            ((lane & 7) ^ ((lane >> 3) & 7)) * 8;
  }
  const float* wb = w_down + (size_t)e * HDIM * IDIM;
  const float* srcB[3];
  int bR[3], bC[3];
  #pragma unroll
  for (int q = 0; q < 3; ++q) {
    int s = tid + 512 * q;
    bR[q] = s >> 3;
    bC[q] = s & 7;
    srcB[q] = wb + (size_t)(c0 + bR[q]) * IDIM + bC[q] * 8;
  }

  fx4 Ra[6], Rb[6];
  #define G2_LOADB(R, k)                                                       \
    {                                                                          \
      _Pragma("unroll") for (int q = 0; q < 3; ++q) {                          \
        R[2 * q] = *(const fx4*)(srcB[q] + (k));                               \
        R[2 * q + 1] = *(const fx4*)(srcB[q] + (k) + 4);                       \
      }                                                                        \
    }
  #define G2_WRITEB(R, bb)                                                     \
    {                                                                          \
      _Pragma("unroll") for (int q = 0; q < 3; ++q)                            \
          *(usx8*)&Bsh[bb][bR[q] * 64 + ((bC[q] ^ (bR[q] & 7)) * 8)] =         \
              cvt8(R[2 * q], R[2 * q + 1]);                                    \
    }
  #define G2_DMA_A(kt, ab)                                                     \
    {                                                                          \
      _Pragma("unroll") for (int j = 0; j < 4; ++j)                            \
          __builtin_amdgcn_global_load_lds(                                    \
              (gas_p)(gA[j] + (size_t)(kt)*BK),                                \
              (las_p)&Ash[ab][(wid * 32 + j * 8) * 64], 16, 0, 0);             \
    }
  #define G2_COMPUTE(ab, bb)                                                   \
    {                                                                          \
      _Pragma("unroll") for (int ks = 0; ks < 2; ++ks) {                       \
        const int rc = ks * 4 + fq;                                            \
        sx8 aF[4], bB[6];                                                      \
        _Pragma("unroll") for (int m = 0; m < 4; ++m) aF[m] =                  \
            *(const sx8*)&Ash[ab][(wm * 64 + m * 16 + fr) * 64 +               \
                                  ((rc ^ (fr & 7)) * 8)];                      \
        _Pragma("unroll") for (int n = 0; n < 6; ++n) bB[n] =                  \
            *(const sx8*)&Bsh[bb][(wn * 96 + n * 16 + fr) * 64 +               \
                                  ((rc ^ (fr & 7)) * 8)];                      \
        __builtin_amdgcn_s_setprio(1);                                         \
        _Pragma("unroll") for (int n = 0; n < 6; ++n)                          \
            _Pragma("unroll") for (int m = 0; m < 4; ++m)                      \
                acc[m][n] = MFMA16(aF[m], bB[n], acc[m][n]);                   \
        __builtin_amdgcn_s_setprio(0);                                         \
      }                                                                        \
    }

  G2_LOADB(Ra, 0);
  G2_LOADB(Rb, BK);
  G2_DMA_A(0, 0);
  __syncthreads();
  G2_WRITEB(Ra, 0);
  __syncthreads();

  for (int tt = 0; tt < 22; ++tt) {
    const int t0 = 2 * tt;
    G2_DMA_A(t0 + 1, 1);
    G2_LOADB(Ra, (t0 + 2) * BK);
    G2_COMPUTE(0, 0);
    G2_WRITEB(Rb, 1);
    __syncthreads();
    G2_DMA_A(t0 + 2, 0);
    const int kodd = (t0 + 3 < NT) ? (t0 + 3) * BK : 0;
    G2_LOADB(Rb, kodd);
    G2_COMPUTE(1, 1);
    G2_WRITEB(Ra, 0);
    __syncthreads();
  }
  G2_COMPUTE(0, 0);  // tile 44

  #pragma unroll
  for (int n = 0; n < 6; ++n) {
    const int col = c0 + wn * 96 + n * 16 + fr;
    const float bias = b_down[e * HDIM + col];
    #pragma unroll
    for (int m = 0; m < 4; ++m) {
      #pragma unroll
      for (int r = 0; r < 4; ++r) {
        int slot = m0 + wm * 64 + m * 16 + fq * 4 + r;
        if (slot < ce) {
          int token = tok[e * NTOK + slot];
          float w = wgt[e * NTOK + slot];
          atomicAdd(&out[(size_t)token * HDIM + col], w * (acc[m][n][r] + bias));
        }
      }
    }
  }
}

extern "C" void kernel_launch(void* const* d_in, const int* in_sizes, int n_in,
                              void* d_out, int out_size, void* d_ws,
                              size_t ws_size, hipStream_t stream) {
  const float* x = (const float*)d_in[0];
  const float* norm_w = (const float*)d_in[1];
  const float* gate_w = (const float*)d_in[2];
  const float* gate_b = (const float*)d_in[3];
  const float* w_gate_up = (const float*)d_in[4];
  const float* b_gate_up = (const float*)d_in[5];
  const float* w_down = (const float*)d_in[6];
  const float* b_down = (const float*)d_in[7];
  float* out = (float*)d_out;

  char* ws = (char*)d_ws;
  unsigned short* t_bf = (unsigned short*)ws;
  ws += (size_t)NTOK * HDIM * 2;
  unsigned short* act_bf = (unsigned short*)ws;
  ws += (size_t)NEXP * NTOK * IDIM * 2;
  int* cnt = (int*)ws;
  ws += 256;
  int* tok = (int*)ws;
  ws += (size_t)NEXP * NTOK * 4;
  float* wgt = (float*)ws;
  ws += (size_t)NEXP * NTOK * 4;

  hipMemsetAsync(cnt, 0, NEXP * sizeof(int), stream);
  init_out_k<<<2880, 256, 0, stream>>>(x, out);
  rms_router_k<<<NTOK, 256, 0, stream>>>(x, norm_w, gate_w, gate_b, t_bf, cnt,
                                         tok, wgt);
  // gemm1: 240 (e,c)-slices x 4 z-twins; twins share h%8 (same XCD), 8 apart.
  gemm1_k<<<960, 512, 0, stream>>>(t_bf, w_gate_up, b_gate_up, cnt, tok,
                                   act_bf);
  // gemm2: 120 slices x 4 z-twins.
  gemm2_k<<<480, 512, 0, stream>>>(act_bf, w_down, b_down, cnt, tok, wgt, out);
}

// Round 12
// 671.028 us; speedup vs baseline: 1.1360x; 1.1360x over previous
//
#include <hip/hip_runtime.h>
#include <hip/hip_bf16.h>

#define NTOK 1024
#define HDIM 2880
#define IDIM 2880
#define NEXP 8
#define BK 64
#define NT 45  // HDIM/BK

typedef __attribute__((ext_vector_type(4))) float fx4;
typedef __attribute__((ext_vector_type(8))) short sx8;
typedef __attribute__((ext_vector_type(8))) unsigned short usx8;

typedef const __attribute__((address_space(1))) void* gas_p;
typedef __attribute__((address_space(3))) void* las_p;

__device__ __forceinline__ unsigned short f2bf(float f) {
  __hip_bfloat16 b = __float2bfloat16(f);
  return __builtin_bit_cast(unsigned short, b);
}
__device__ __forceinline__ usx8 cvt8(fx4 a, fx4 b) {
  usx8 u = {f2bf(a.x), f2bf(a.y), f2bf(a.z), f2bf(a.w),
            f2bf(b.x), f2bf(b.y), f2bf(b.z), f2bf(b.w)};
  return u;
}

#define MFMA16(a, b, c) __builtin_amdgcn_mfma_f32_16x16x32_bf16(a, b, c, 0, 0, 0)

__global__ __launch_bounds__(256) void init_out_k(const float* __restrict__ x,
                                                  float* __restrict__ out) {
  int i = blockIdx.x * 256 + threadIdx.x;
  ((fx4*)out)[i] = ((const fx4*)x)[i];
}

// streaming fp32 -> bf16 (n8 = elements/8)
__global__ __launch_bounds__(256) void cvt_bf_k(const float* __restrict__ src,
                                                unsigned short* __restrict__ dst,
                                                long n8) {
  const long stride = (long)gridDim.x * 256;
  for (long i = (long)blockIdx.x * 256 + threadIdx.x; i < n8; i += stride) {
    fx4 a = *(const fx4*)(src + i * 8);
    fx4 b = *(const fx4*)(src + i * 8 + 4);
    *(usx8*)(dst + i * 8) = cvt8(a, b);
  }
}

__global__ __launch_bounds__(256) void rms_router_k(
    const float* __restrict__ x, const float* __restrict__ norm_w,
    const float* __restrict__ gate_w, const float* __restrict__ gate_b,
    unsigned short* __restrict__ t_bf, int* __restrict__ cnt,
    int* __restrict__ tok, float* __restrict__ wgt) {
  const int n = blockIdx.x;
  const int tid = threadIdx.x;
  const int wid = tid >> 6, lane = tid & 63;
  const float* xr = x + (size_t)n * HDIM;

  float ss = 0.f;
  for (int h = tid; h < HDIM; h += 256) { float v = xr[h]; ss += v * v; }
  #pragma unroll
  for (int o = 32; o > 0; o >>= 1) ss += __shfl_down(ss, o);
  __shared__ float sred[4];
  if (lane == 0) sred[wid] = ss;
  __syncthreads();
  const float rstd =
      rsqrtf((sred[0] + sred[1] + sred[2] + sred[3]) * (1.0f / HDIM) + 1e-5f);

  float p[NEXP];
  #pragma unroll
  for (int e = 0; e < NEXP; e++) p[e] = 0.f;
  for (int h = tid; h < HDIM; h += 256) {
    float xv = xr[h] * norm_w[h];
    t_bf[(size_t)n * HDIM + h] = f2bf(xv * rstd);
    #pragma unroll
    for (int e = 0; e < NEXP; e++) p[e] += xv * gate_w[e * HDIM + h];
  }
  __shared__ float pls[4][NEXP];
  #pragma unroll
  for (int e = 0; e < NEXP; e++) {
    float v = p[e];
    #pragma unroll
    for (int o = 32; o > 0; o >>= 1) v += __shfl_down(v, o);
    if (lane == 0) pls[wid][e] = v;
  }
  __syncthreads();
  if (tid == 0) {
    float lg[NEXP];
    #pragma unroll
    for (int e = 0; e < NEXP; e++)
      lg[e] = (pls[0][e] + pls[1][e] + pls[2][e] + pls[3][e]) * rstd + gate_b[e];
    unsigned used = 0;
    float val[4];
    int idx[4];
    for (int k = 0; k < 4; k++) {
      float best = -1e30f;
      int bi = 0;
      for (int e = 0; e < NEXP; e++)
        if (!((used >> e) & 1u) && lg[e] > best) { best = lg[e]; bi = e; }
      used |= 1u << bi;
      val[k] = best;
      idx[k] = bi;
    }
    float sum = 0.f, w[4];
    for (int k = 0; k < 4; k++) { w[k] = expf(val[k] - val[0]); sum += w[k]; }
    for (int k = 0; k < 4; k++) {
      int e = idx[k];
      int slot = atomicAdd(&cnt[e], 1);
      tok[e * NTOK + slot] = n;
      wgt[e * NTOK + slot] = w[k] / sum;
    }
  }
}

// GEMM1 (m97 structure): 128 tokens x (64 G + 64 L), BK=64, 4 waves (2x2),
// single-buf 32 KB, 3 blocks/CU. Both operands via global_load_lds (bf16)
// with verified 0-conflict XOR pre-swizzle. Fallback: in-loop fp32 cvt.
template <bool BF16B>
__global__ __launch_bounds__(256, 3) void gemm1_k(
    const unsigned short* __restrict__ t_bf,
    const unsigned short* __restrict__ wgu_bf,
    const float* __restrict__ w_gate_up, const float* __restrict__ b_gate_up,
    const int* __restrict__ cnt, const int* __restrict__ tok,
    unsigned short* __restrict__ act_bf) {
  const int h = blockIdx.x;
  const int g = h >> 6, z = (h >> 3) & 7, v = h & 7;
  const int u = g * 8 + v;        // (e, col-slice), < 360
  const int e = u / 45;
  const int c0 = (u % 45) * 64;   // FIX r11: 45 slices x 64 I-cols = 2880
  const int m0 = z * 128;
  const int ce = cnt[e];
  if (m0 >= ce) return;

  const int tid = threadIdx.x, lane = tid & 63, wid = tid >> 6;
  const int fr = lane & 15, fq = lane >> 4;
  const int wm = wid >> 1, wn = wid & 1;
  const int sw = ((lane & 7) ^ ((lane >> 3) & 7)) * 8;  // DMA source pre-swizzle

  __shared__ __align__(16) unsigned short Ash[128 * 64];  // 16 KB
  __shared__ __align__(16) unsigned short Bsh[128 * 64];  // 16 KB (G:0-63 L:64-127)

  const fx4 FZ = {0.f, 0.f, 0.f, 0.f};
  fx4 accG[4][2], accL[4][2];
  #pragma unroll
  for (int m = 0; m < 4; m++)
    #pragma unroll
    for (int n = 0; n < 2; n++) { accG[m][n] = FZ; accL[m][n] = FZ; }

  // A: 4 DMA per wave, 8 rows each (128B rows).
  const unsigned short* gA[4];
  #pragma unroll
  for (int j = 0; j < 4; ++j) {
    int R = m0 + wid * 32 + j * 8 + (lane >> 3);
    int rc = R < ce ? R : ce - 1;
    gA[j] = t_bf + (size_t)tok[e * NTOK + rc] * HDIM + sw;
  }
  // B (bf16 path): 128 weight rows (64 G + 64 L), 4 DMA per wave.
  const unsigned short* gB[4];
  #pragma unroll
  for (int j = 0; j < 4; ++j) {
    int br = wid * 32 + j * 8 + (lane >> 3);
    int wr = br < 64 ? (c0 + br) : (IDIM + c0 + (br - 64));
    gB[j] = wgu_bf + ((size_t)e * (2 * IDIM) + wr) * HDIM + sw;
  }
  // B (fp32 fallback): 1024 chunk-slots, 4 per thread.
  const float* fB[4];
  int fRow[4], fCh[4];
  if constexpr (!BF16B) {
    #pragma unroll
    for (int q = 0; q < 4; ++q) {
      int s = tid + 256 * q;
      fRow[q] = s >> 3;
      fCh[q] = s & 7;
      int wr = fRow[q] < 64 ? (c0 + fRow[q]) : (IDIM + c0 + (fRow[q] - 64));
      fB[q] = w_gate_up + ((size_t)e * (2 * IDIM) + wr) * HDIM + fCh[q] * 8;
    }
  }

  for (int t = 0; t < NT; ++t) {
    const int ko = t * BK;
    __syncthreads();
    #pragma unroll
    for (int j = 0; j < 4; ++j)
      __builtin_amdgcn_global_load_lds((gas_p)(gA[j] + ko),
                                       (las_p)&Ash[(wid * 32 + j * 8) * 64], 16,
                                       0, 0);
    if constexpr (BF16B) {
      #pragma unroll
      for (int j = 0; j < 4; ++j)
        __builtin_amdgcn_global_load_lds((gas_p)(gB[j] + ko),
                                         (las_p)&Bsh[(wid * 32 + j * 8) * 64],
                                         16, 0, 0);
    } else {
      #pragma unroll
      for (int q = 0; q < 4; ++q) {
        fx4 a = *(const fx4*)(fB[q] + ko);
        fx4 b = *(const fx4*)(fB[q] + ko + 4);
        *(usx8*)&Bsh[fRow[q] * 64 + ((fCh[q] ^ (fRow[q] & 7)) * 8)] = cvt8(a, b);
      }
    }
    __syncthreads();
    #pragma unroll
    for (int ks = 0; ks < 2; ++ks) {
      const int rc = ks * 4 + fq;
      sx8 aF[4], bG[2], bL[2];
      #pragma unroll
      for (int m = 0; m < 4; ++m)
        aF[m] = *(const sx8*)&Ash[(wm * 64 + m * 16 + fr) * 64 +
                                  ((rc ^ (fr & 7)) * 8)];
      #pragma unroll
      for (int n = 0; n < 2; ++n) {
        bG[n] = *(const sx8*)&Bsh[(wn * 32 + n * 16 + fr) * 64 +
                                  ((rc ^ (fr & 7)) * 8)];
        bL[n] = *(const sx8*)&Bsh[(64 + wn * 32 + n * 16 + fr) * 64 +
                                  ((rc ^ (fr & 7)) * 8)];
      }
      #pragma unroll
      for (int n = 0; n < 2; ++n)
        #pragma unroll
        for (int m = 0; m < 4; ++m) {
          accG[m][n] = MFMA16(aF[m], bG[n], accG[m][n]);
          accL[m][n] = MFMA16(aF[m], bL[n], accL[m][n]);
        }
    }
  }

  #pragma unroll
  for (int n = 0; n < 2; ++n) {
    const int col = c0 + wn * 32 + n * 16 + fr;
    const float bg = b_gate_up[e * (2 * IDIM) + col];
    const float bl = b_gate_up[e * (2 * IDIM) + IDIM + col];
    #pragma unroll
    for (int m = 0; m < 4; ++m) {
      #pragma unroll
      for (int r = 0; r < 4; ++r) {
        int slot = m0 + wm * 64 + m * 16 + fq * 4 + r;
        if (slot < ce) {
          float gv = accG[m][n][r] + bg;
          float lv = accL[m][n][r] + bl;
          float a = gv * (1.0f / (1.0f + __expf(-1.702f * gv))) * (lv + 1.0f);
          act_bf[((size_t)e * NTOK + slot) * IDIM + col] = f2bf(a);
        }
      }
    }
  }
}

// GEMM2 (m97 structure): 128 rows x 96 cols, BK=64, 4 waves (2x2),
// single-buf 28 KB, 3 blocks/CU.
template <bool BF16B>
__global__ __launch_bounds__(256, 3) void gemm2_k(
    const unsigned short* __restrict__ act_bf,
    const unsigned short* __restrict__ wd_bf, const float* __restrict__ w_down,
    const float* __restrict__ b_down, const int* __restrict__ cnt,
    const int* __restrict__ tok, const float* __restrict__ wgt,
    float* __restrict__ out) {
  const int h = blockIdx.x;
  const int g = h >> 6, z = (h >> 3) & 7, v = h & 7;
  const int u = g * 8 + v;            // < 240
  const int e = u / 30;
  const int c0 = (u % 30) * 96;
  const int m0 = z * 128;
  const int ce = cnt[e];
  if (m0 >= ce) return;

  const int tid = threadIdx.x, lane = tid & 63, wid = tid >> 6;
  const int fr = lane & 15, fq = lane >> 4;
  const int wm = wid >> 1, wn = wid & 1;
  const int sw = ((lane & 7) ^ ((lane >> 3) & 7)) * 8;

  __shared__ __align__(16) unsigned short Ash[128 * 64];  // 16 KB
  __shared__ __align__(16) unsigned short Bsh[96 * 64];   // 12 KB

  const fx4 FZ = {0.f, 0.f, 0.f, 0.f};
  fx4 acc[4][3];
  #pragma unroll
  for (int m = 0; m < 4; m++)
    #pragma unroll
    for (int n = 0; n < 3; n++) acc[m][n] = FZ;

  const unsigned short* gA[4];
  #pragma unroll
  for (int j = 0; j < 4; ++j) {
    int R = m0 + wid * 32 + j * 8 + (lane >> 3);
    int rc = R < ce ? R : ce - 1;
    gA[j] = act_bf + ((size_t)e * NTOK + rc) * IDIM + sw;
  }
  // B: 96 rows, 3 DMA per wave (24 rows/wave).
  const unsigned short* gB[3];
  #pragma unroll
  for (int j = 0; j < 3; ++j) {
    int br = wid * 24 + j * 8 + (lane >> 3);
    gB[j] = wd_bf + ((size_t)e * HDIM + c0 + br) * IDIM + sw;
  }
  const float* fB[3];
  int fRow[3], fCh[3];
  if constexpr (!BF16B) {
    #pragma unroll
    for (int q = 0; q < 3; ++q) {
      int s = tid + 256 * q;  // 768 slots
      fRow[q] = s >> 3;
      fCh[q] = s & 7;
      fB[q] = w_down + ((size_t)e * HDIM + c0 + fRow[q]) * IDIM + fCh[q] * 8;
    }
  }

  for (int t = 0; t < NT; ++t) {
    const int ko = t * BK;
    __syncthreads();
    #pragma unroll
    for (int j = 0; j < 4; ++j)
      __builtin_amdgcn_global_load_lds((gas_p)(gA[j] + ko),
                                       (las_p)&Ash[(wid * 32 + j * 8) * 64], 16,
                                       0, 0);
    if constexpr (BF16B) {
      #pragma unroll
      for (int j = 0; j < 3; ++j)
        __builtin_amdgcn_global_load_lds((gas_p)(gB[j] + ko),
                                         (las_p)&Bsh[(wid * 24 + j * 8) * 64],
                                         16, 0, 0);
    } else {
      #pragma unroll
      for (int q = 0; q < 3; ++q) {
        fx4 a = *(const fx4*)(fB[q] + ko);
        fx4 b = *(const fx4*)(fB[q] + ko + 4);
        *(usx8*)&Bsh[fRow[q] * 64 + ((fCh[q] ^ (fRow[q] & 7)) * 8)] = cvt8(a, b);
      }
    }
    __syncthreads();
    #pragma unroll
    for (int ks = 0; ks < 2; ++ks) {
      const int rc = ks * 4 + fq;
      sx8 aF[4], bB[3];
      #pragma unroll
      for (int m = 0; m < 4; ++m)
        aF[m] = *(const sx8*)&Ash[(wm * 64 + m * 16 + fr) * 64 +
                                  ((rc ^ (fr & 7)) * 8)];
      #pragma unroll
      for (int n = 0; n < 3; ++n)
        bB[n] = *(const sx8*)&Bsh[(wn * 48 + n * 16 + fr) * 64 +
                                  ((rc ^ (fr & 7)) * 8)];
      #pragma unroll
      for (int n = 0; n < 3; ++n)
        #pragma unroll
        for (int m = 0; m < 4; ++m)
          acc[m][n] = MFMA16(aF[m], bB[n], acc[m][n]);
    }
  }

  #pragma unroll
  for (int n = 0; n < 3; ++n) {
    const int col = c0 + wn * 48 + n * 16 + fr;
    const float bias = b_down[e * HDIM + col];
    #pragma unroll
    for (int m = 0; m < 4; ++m) {
      #pragma unroll
      for (int r = 0; r < 4; ++r) {
        int slot = m0 + wm * 64 + m * 16 + fq * 4 + r;
        if (slot < ce) {
          int token = tok[e * NTOK + slot];
          float w = wgt[e * NTOK + slot];
          atomicAdd(&out[(size_t)token * HDIM + col], w * (acc[m][n][r] + bias));
        }
      }
    }
  }
}

extern "C" void kernel_launch(void* const* d_in, const int* in_sizes, int n_in,
                              void* d_out, int out_size, void* d_ws,
                              size_t ws_size, hipStream_t stream) {
  const float* x = (const float*)d_in[0];
  const float* norm_w = (const float*)d_in[1];
  const float* gate_w = (const float*)d_in[2];
  const float* gate_b = (const float*)d_in[3];
  const float* w_gate_up = (const float*)d_in[4];
  const float* b_gate_up = (const float*)d_in[5];
  const float* w_down = (const float*)d_in[6];
  const float* b_down = (const float*)d_in[7];
  float* out = (float*)d_out;

  char* ws = (char*)d_ws;
  size_t off = 0;
  unsigned short* t_bf = (unsigned short*)(ws + off);
  off += (size_t)NTOK * HDIM * 2;
  unsigned short* act_bf = (unsigned short*)(ws + off);
  off += (size_t)NEXP * NTOK * IDIM * 2;
  int* cnt = (int*)(ws + off);
  off += 256;
  int* tok = (int*)(ws + off);
  off += (size_t)NEXP * NTOK * 4;
  float* wgt = (float*)(ws + off);
  off += (size_t)NEXP * NTOK * 4;

  const size_t WD_E = (size_t)NEXP * HDIM * IDIM;       // 66.4M elems
  const size_t WGU_E = (size_t)NEXP * 2 * IDIM * HDIM;  // 132.7M elems
  unsigned short* wd_bf = (unsigned short*)(ws + off);
  const bool haveWd = (off + WD_E * 2) <= ws_size;
  if (haveWd) off += WD_E * 2;
  unsigned short* wgu_bf = (unsigned short*)(ws + off);
  const bool haveWgu = (off + WGU_E * 2) <= ws_size;

  hipMemsetAsync(cnt, 0, NEXP * sizeof(int), stream);
  init_out_k<<<2880, 256, 0, stream>>>(x, out);
  if (haveWgu)
    cvt_bf_k<<<4096, 256, 0, stream>>>(w_gate_up, wgu_bf, (long)(WGU_E / 8));
  if (haveWd)
    cvt_bf_k<<<4096, 256, 0, stream>>>(w_down, wd_bf, (long)(WD_E / 8));
  rms_router_k<<<NTOK, 256, 0, stream>>>(x, norm_w, gate_w, gate_b, t_bf, cnt,
                                         tok, wgt);
  // h = g*64 + z*8 + v: the 8 z-twins of each (e,c) share h%8 (same XCD)
  // within a 64-block window -> weight panel fetched from HBM once.
  if (haveWgu)
    gemm1_k<true><<<2880, 256, 0, stream>>>(t_bf, wgu_bf, w_gate_up, b_gate_up,
                                            cnt, tok, act_bf);
  else
    gemm1_k<false><<<2880, 256, 0, stream>>>(t_bf, nullptr, w_gate_up,
                                             b_gate_up, cnt, tok, act_bf);
  if (haveWd)
    gemm2_k<true><<<1920, 256, 0, stream>>>(act_bf, wd_bf, w_down, b_down, cnt,
                                            tok, wgt, out);
  else
    gemm2_k<false><<<1920, 256, 0, stream>>>(act_bf, nullptr, w_down, b_down,
                                             cnt, tok, wgt, out);
}